// Round 11
// baseline (508.038 us; speedup 1.0000x reference)
//
#include <hip/hip_runtime.h>

typedef unsigned short u16;
typedef __attribute__((ext_vector_type(8))) short short8;
typedef __attribute__((ext_vector_type(4))) float f32x4;

#define Bn 4096
#define Vn 20
#define Dn 768
#define Mn (Bn * Vn)   // 81920 rows
#define Nn (2 * Dn)    // 1536 packed m1/m2 columns

#define BM 256
#define BNt 128            // Wt rows per block tile (= 64 output e-columns)
#define HK 32              // K per slice
#define NHK (Dn / HK)      // 24 slices
#define NTILES (Nn / BNt)  // 12 N-tiles
#define GRID ((Mn / BM) * NTILES)   // 320 * 12 = 3840, %8 == 0

typedef __attribute__((address_space(1))) void GV;
typedef __attribute__((address_space(3))) void LV;

__device__ __forceinline__ u16 f2bf(float f) {
  union { float f; unsigned u; } v; v.f = f;
  unsigned r = v.u + 0x7FFFu + ((v.u >> 16) & 1u);  // round-to-nearest-even
  return (u16)(r >> 16);
}
__device__ __forceinline__ float bf2f(u16 x) {
  union { unsigned u; float f; } v; v.u = ((unsigned)x) << 16; return v.f;
}

// B LDS map within a 128x32 (rows x K) u16 slot (proven 0-conflict R6-R10):
//   idx = (r>>1)*64 + (r&1)*32 + ((kc ^ ((r>>1)&3))*8) + j
__device__ __forceinline__ int lds_off(int r, int hi) {
  return (r >> 1) * 64 + (r & 1) * 32 + ((hi ^ ((r >> 1) & 3)) * 8);
}
// conv-epilogue LDS map: [c][r] col-major with row-XOR swizzle
__device__ __forceinline__ int fsw(int c, int r) {
  return c * 256 + (r ^ ((c & 31) << 3));
}

// ---- kernel 1: softmax, 16 rows/block, writes X' FRAGMENT-MAJOR -----------
// X' u16 index = g*12288 + kc*128 + lo*8 + j  (g=row>>4, lo=row&15, kc=k>>3)
// => a GEMM A-fragment (16 rows x 8 k x 4 kc) is 1KB CONTIGUOUS.
__global__ __launch_bounds__(256) void softmax_k(const float* __restrict__ vf,
                                                 u16* __restrict__ Xp) {
  __shared__ float red[2][16][4];
  const int t = threadIdx.x, lo = t & 15, seg = t >> 4, wv = t >> 6;
  const size_t g = blockIdx.x;
  const float4* src = (const float4*)(vf + ((size_t)g * 16 + lo) * Dn + seg * 48);
  float4 v[12];
  #pragma unroll
  for (int q = 0; q < 12; ++q) v[q] = src[q];
  float mx = -1e30f;
  #pragma unroll
  for (int q = 0; q < 12; ++q)
    mx = fmaxf(mx, fmaxf(fmaxf(v[q].x, v[q].y), fmaxf(v[q].z, v[q].w)));
  mx = fmaxf(mx, __shfl_xor(mx, 16));
  mx = fmaxf(mx, __shfl_xor(mx, 32));
  if ((t & 63) < 16) red[0][lo][wv] = mx;
  __syncthreads();
  mx = fmaxf(fmaxf(red[0][lo][0], red[0][lo][1]),
             fmaxf(red[0][lo][2], red[0][lo][3]));
  float s = 0.f;
  #pragma unroll
  for (int q = 0; q < 12; ++q) {
    v[q].x = __expf(v[q].x - mx); v[q].y = __expf(v[q].y - mx);
    v[q].z = __expf(v[q].z - mx); v[q].w = __expf(v[q].w - mx);
    s += (v[q].x + v[q].y) + (v[q].z + v[q].w);
  }
  s += __shfl_xor(s, 16);
  s += __shfl_xor(s, 32);
  if ((t & 63) < 16) red[1][lo][wv] = s;
  __syncthreads();
  const float inv = 1.0f / (red[1][lo][0] + red[1][lo][1] +
                            red[1][lo][2] + red[1][lo][3]);
  u16* dst = Xp + (size_t)g * 12288 + seg * 768 + lo * 8;   // kc = seg*6 + c
  #pragma unroll
  for (int c = 0; c < 6; ++c) {
    float4 a = v[2 * c], b = v[2 * c + 1];
    short8 o;
    o[0] = (short)f2bf(a.x * inv); o[1] = (short)f2bf(a.y * inv);
    o[2] = (short)f2bf(a.z * inv); o[3] = (short)f2bf(a.w * inv);
    o[4] = (short)f2bf(b.x * inv); o[5] = (short)f2bf(b.y * inv);
    o[6] = (short)f2bf(b.z * inv); o[7] = (short)f2bf(b.w * inv);
    *(short8*)(dst + c * 128) = o;
  }
}

// ------- kernel 2: pack W1/W2 block-of-32 interleaved, bf16 [1536][768] -----
__global__ __launch_bounds__(256) void build_wt_k(const float* __restrict__ W1,
                                                  const float* __restrict__ W2,
                                                  u16* __restrict__ Wt) {
  int idx = blockIdx.x * 256 + threadIdx.x;
  if (idx >= Dn * Dn) return;
  int j = idx / Dn, d = idx - j * Dn;
  int b = j >> 5, c = j & 31;
  Wt[(size_t)(b * 64 + c) * Dn + d]      = f2bf(W1[(size_t)j * Dn + d]);
  Wt[(size_t)(b * 64 + 32 + c) * Dn + d] = f2bf(W2[(size_t)j * Dn + d]);
}

// -------- kernel 3: GEMM with A direct-to-registers + fused conv epilogue ---
// 8 waves (4M x 2N), wave tile 64x64, 24 K-slices of 32.
// A: per-wave async global_load_dwordx4 from fragment-major X' (1KB dense per
// inst), triple-buffered in regs (sets af0/1/2), consumed 2 slices after
// issue. NO LDS for A. B: 3-slot x 8KB LDS ring via global_load_lds.
// Slice s: vmcnt(5) [1 slice of 5 loads in flight] -> barrier -> 4 ds_read B
// -> lgkm0 -> prio1 16 MFMA prio0 -> stage B(s+2) + issue A(s+2).
// Staging at the END keeps any compiler-inserted drain cheap (youngest
// outstanding loads are >=1 slice old at MFMA time).
__global__ __launch_bounds__(512, 2) void gemm_fuse_k(
    const u16* __restrict__ Xp, const u16* __restrict__ Wt,
    const float* __restrict__ b1, const float* __restrict__ b2,
    const float* __restrict__ text, float* __restrict__ out,
    u16* __restrict__ seam,
    const float* __restrict__ cw1, const float* __restrict__ cb1,
    const float* __restrict__ cw2, const float* __restrict__ cb2) {
  __shared__ __align__(16) u16 smem[32768];   // 64 KiB (K-loop uses 24 KiB)

  const int h = blockIdx.x;                      // GRID = 3840, %8==0
  const int lin = (h & 7) * (GRID / 8) + (h >> 3);
  const int by = lin / NTILES, bx = lin - by * NTILES;
  const int brow = by * BM;

  const int t = threadIdx.x, w = t >> 6, l = t & 63;
  const int lo = l & 15, hi = l >> 4;
  const int wrr = w >> 1, wcc = w & 1;           // 4M x 2N

  int offB[4];
  #pragma unroll
  for (int n = 0; n < 4; ++n) offB[n] = lds_off(wcc * 64 + n * 16 + lo, hi);

  // A: per-lane fragment-major base; frag(m, s) = aptr + m*12288 + s*512
  const u16* aptr = Xp + (size_t)(by * 16 + wrr * 4) * 12288 + hi * 128 + lo * 8;

  // B staging source (thread q=t fills slot u16 [t*8..t*8+8))
  const u16* gB;
  {
    int rp = t >> 3, half = (t >> 2) & 1, kc = (t & 3) ^ (rp & 3);
    gB = Wt + (size_t)(bx * BNt + rp * 2 + half) * Dn + kc * 8;
  }

#define STB(S) __builtin_amdgcn_global_load_lds((GV*)(gB + (S) * HK), \
      (LV*)(smem + ((S) % 3) * 4096 + t * 8), 16, 0, 0)
#define LDA(SET, S) do { _Pragma("unroll") for (int m = 0; m < 4; ++m) \
      SET[m] = *(const short8*)(aptr + m * 12288 + (S) * 512); } while (0)

  short8 af0[4], af1[4], af2[4];
  // prologue ledger: [B0, A0x4, B1, A1x4] = 10 in flight
  STB(0); LDA(af0, 0);
  STB(1); LDA(af1, 1);

  f32x4 acc[4][4] = {};

#define SLICE(S, CUR, NXT) do {                                                \
    if ((S) < 22) asm volatile("s_waitcnt vmcnt(5)" ::: "memory");             \
    else          asm volatile("s_waitcnt vmcnt(0)" ::: "memory");             \
    __builtin_amdgcn_s_barrier();                                              \
    { const u16* sb_ = smem + ((S) % 3) * 4096;                                \
      short8 b0_ = *(const short8*)(sb_ + offB[0]);                            \
      short8 b1_ = *(const short8*)(sb_ + offB[1]);                            \
      short8 b2_ = *(const short8*)(sb_ + offB[2]);                            \
      short8 b3_ = *(const short8*)(sb_ + offB[3]);                            \
      asm volatile("s_waitcnt lgkmcnt(0)" ::: "memory");                       \
      __builtin_amdgcn_sched_barrier(0);                                       \
      __builtin_amdgcn_s_setprio(1);                                           \
      _Pragma("unroll") for (int m = 0; m < 4; ++m) {                          \
        acc[m][0] = __builtin_amdgcn_mfma_f32_16x16x32_bf16(CUR[m], b0_, acc[m][0], 0, 0, 0); \
        acc[m][1] = __builtin_amdgcn_mfma_f32_16x16x32_bf16(CUR[m], b1_, acc[m][1], 0, 0, 0); \
        acc[m][2] = __builtin_amdgcn_mfma_f32_16x16x32_bf16(CUR[m], b2_, acc[m][2], 0, 0, 0); \
        acc[m][3] = __builtin_amdgcn_mfma_f32_16x16x32_bf16(CUR[m], b3_, acc[m][3], 0, 0, 0); \
      }                                                                        \
      __builtin_amdgcn_s_setprio(0);                                           \
    }                                                                          \
    if ((S) < 22) { STB((S) + 2); LDA(NXT, (S) + 2); }                         \
  } while (0)

  #pragma unroll
  for (int s3 = 0; s3 < 8; ++s3) {
    SLICE(3 * s3 + 0, af0, af2);
    SLICE(3 * s3 + 1, af1, af0);
    SLICE(3 * s3 + 2, af2, af1);
  }
#undef SLICE
#undef STB
#undef LDA

  __syncthreads();   // all slot-reads done before LDS reuse by epilogue

  // ======================= fused-conv epilogue ==============================
  const float w10 = cw1[0], w11 = cw1[1], w12 = cw1[2], c1b = cb1[0];
  const float w20 = cw2[0], w21 = cw2[1], w22 = cw2[2], c2b = cb2[0];

  u16* fsm = smem;           // fused [64 c][256 r], swizzled: 32 KiB
  u16* tsm = smem + 16384;   // tmp, same layout: 32 KiB

  // ---- E1: fused -> LDS bf16 (+ seam store for cols 0-3, 60-63) ----
  #pragma unroll
  for (int n = 0; n < 2; ++n) {
    const int cl = wcc * 32 + n * 16 + lo;       // local col 0..63
    const int e  = bx * 64 + cl;
    const float B1 = b1[e], B2 = b2[e];
    #pragma unroll
    for (int m = 0; m < 4; ++m) {
      const int rl = wrr * 64 + m * 16 + hi * 4;
      uint2 pk;
      u16* pku = (u16*)&pk;
      #pragma unroll
      for (int r = 0; r < 4; ++r) {
        const int gr = brow + rl + r;
        const float v1 = acc[m][n][r] + B1;
        const float v2 = acc[m][n + 2][r] + B2;
        const float tf = text[(size_t)(gr / Vn) * Dn + e];
        pku[r] = f2bf(fmaxf(tf * v1 + v2, 0.0f));
      }
      *(uint2*)(fsm + fsw(cl, rl)) = pk;
      const int sidx = (cl < 4) ? cl : ((cl >= 60) ? cl - 56 : -1);
      if (sidx >= 0)
        *(uint2*)(seam + ((size_t)(by * NTILES + bx) * 8 + sidx) * 256 + rl) = pk;
    }
  }
  __syncthreads();

  // ---- E2: tmp = relu(conv1(fused)); own col kept in regs ----
  const int cl = t & 63, rb = t >> 6;            // 8 row-groups of 32
  const int cL = cl ? cl - 1 : 0, cR = (cl < 63) ? cl + 1 : 63;
  short8 tC[4];
  #pragma unroll
  for (int j = 0; j < 4; ++j) {
    const int R = rb * 32 + j * 8;
    short8 sL = *(const short8*)(fsm + fsw(cL, R));
    short8 sC = *(const short8*)(fsm + fsw(cl, R));
    short8 sR = *(const short8*)(fsm + fsw(cR, R));
    short8 o;
    #pragma unroll
    for (int k = 0; k < 8; ++k) {
      float a = bf2f((u16)sL[k]), b = bf2f((u16)sC[k]), c = bf2f((u16)sR[k]);
      o[k] = (short)f2bf(fmaxf(fmaf(w10, a, fmaf(w11, b, fmaf(w12, c, c1b))), 0.0f));
    }
    *(short8*)(tsm + fsw(cl, R)) = o;
    tC[j] = o;
  }
  __syncthreads();

  // ---- E3: out = conv2(tmp), store interior cols 2..61 ----
  const bool wr_ok = (cl >= 2 && cl <= 61);
  #pragma unroll
  for (int j = 0; j < 4; ++j) {
    const int R = rb * 32 + j * 8;
    short8 tL = *(const short8*)(tsm + fsw(cL, R));
    short8 tR = *(const short8*)(tsm + fsw(cR, R));
    #pragma unroll
    for (int k = 0; k < 8; ++k) {
      float v = fmaf(w20, bf2f((u16)tL[k]),
                fmaf(w21, bf2f((u16)tC[j][k]),
                fmaf(w22, bf2f((u16)tR[k]), c2b)));
      if (wr_ok)
        out[(size_t)(brow + R + k) * Dn + bx * 64 + cl] = v;
    }
  }
}

// ------- kernel 4: seam cleanup — out cols {E0,E0+1,E0+62,E0+63} -----------
__global__ __launch_bounds__(256) void seam_k(const u16* __restrict__ seam,
                                              float* __restrict__ out,
                                              const float* __restrict__ cw1,
                                              const float* __restrict__ cb1,
                                              const float* __restrict__ cw2,
                                              const float* __restrict__ cb2) {
  const int bid = blockIdx.x;          // by*12+bx
  const int by = bid / NTILES, bx = bid - by * NTILES;
  const int r = threadIdx.x;
  const float w10 = cw1[0], w11 = cw1[1], w12 = cw1[2], c1b = cb1[0];
  const float w20 = cw2[0], w21 = cw2[1], w22 = cw2[2], c2b = cb2[0];
  #define SM(B, I) bf2f(seam[((size_t)(B) * 8 + (I)) * 256 + r])
  float fm2 = 0.f, fm1 = 0.f, fR0 = 0.f, fR1 = 0.f;
  if (bx > 0)          { fm2 = SM(bid - 1, 6); fm1 = SM(bid - 1, 7); }
  if (bx < NTILES - 1) { fR0 = SM(bid + 1, 0); fR1 = SM(bid + 1, 1); }
  const float f0 = SM(bid, 0), f1 = SM(bid, 1), f2 = SM(bid, 2), f3 = SM(bid, 3);
  const float f60 = SM(bid, 4), f61 = SM(bid, 5), f62 = SM(bid, 6), f63 = SM(bid, 7);
  #undef SM
  #define C1(a, b, c) fmaxf(fmaf(w10, (a), fmaf(w11, (b), fmaf(w12, (c), c1b))), 0.0f)
  const float tm1 = (bx > 0) ? C1(fm2, fm1, f0) : 0.0f;
  const float t0  = C1(fm1, f0, f1);
  const float t1  = C1(f0, f1, f2);
  const float t2  = C1(f1, f2, f3);
  const float t61 = C1(f60, f61, f62);
  const float t62 = C1(f61, f62, f63);
  const float t63 = C1(f62, f63, fR0);
  const float t64 = (bx < NTILES - 1) ? C1(f63, fR0, fR1) : 0.0f;
  #undef C1
  const size_t go = (size_t)(by * 256 + r) * Dn + bx * 64;
  out[go + 0]  = fmaf(w20, tm1, fmaf(w21, t0,  fmaf(w22, t1,  c2b)));
  out[go + 1]  = fmaf(w20, t0,  fmaf(w21, t1,  fmaf(w22, t2,  c2b)));
  out[go + 62] = fmaf(w20, t61, fmaf(w21, t62, fmaf(w22, t63, c2b)));
  out[go + 63] = fmaf(w20, t62, fmaf(w21, t63, fmaf(w22, t64, c2b)));
}

extern "C" void kernel_launch(void* const* d_in, const int* in_sizes, int n_in,
                              void* d_out, int out_size, void* d_ws, size_t ws_size,
                              hipStream_t stream) {
  const float* text = (const float*)d_in[0];
  const float* vf   = (const float*)d_in[1];
  const float* W1   = (const float*)d_in[2];
  const float* b1   = (const float*)d_in[3];
  const float* W2   = (const float*)d_in[4];
  const float* b2   = (const float*)d_in[5];
  const float* cw1  = (const float*)d_in[6];
  const float* cb1  = (const float*)d_in[7];
  const float* cw2  = (const float*)d_in[8];
  const float* cb2  = (const float*)d_in[9];
  float* out = (float*)d_out;

  u16* Xp   = (u16*)d_ws;                        // [5120 groups][12288] bf16
  u16* Wt   = Xp + (size_t)Mn * Dn;              // [1536][768] bf16
  u16* seam = Wt + (size_t)Nn * Dn;              // [3840][8][256] bf16

  softmax_k<<<Mn / 16, 256, 0, stream>>>(vf, Xp);
  build_wt_k<<<(Dn * Dn + 255) / 256, 256, 0, stream>>>(W1, W2, Wt);
  gemm_fuse_k<<<GRID, 512, 0, stream>>>(Xp, Wt, b1, b2, text, out, seam,
                                        cw1, cb1, cw2, cb2);
  seam_k<<<GRID, 256, 0, stream>>>(seam, out, cw1, cb1, cw2, cb2);
}

// Round 13
// 399.789 us; speedup vs baseline: 1.2708x; 1.2708x over previous
//
#include <hip/hip_runtime.h>

typedef unsigned short u16;
typedef __attribute__((ext_vector_type(8))) short short8;
typedef __attribute__((ext_vector_type(4))) float f32x4;

#define Bn 4096
#define Vn 20
#define Dn 768
#define Mn (Bn * Vn)   // 81920 rows
#define Nn (2 * Dn)    // 1536 packed m1/m2 columns

#define BM 256
#define BNt 128            // Wt rows per block tile (= 64 output e-columns)
#define HK 32              // K per slice
#define NHK (Dn / HK)      // 24 slices
#define NTILES (Nn / BNt)  // 12 N-tiles
#define GRID ((Mn / BM) * NTILES)   // 320 * 12 = 3840, %8 == 0
#define SLOTU 12288        // u16 per slot: A 256x32 (8192) + B 128x32 (4096)

typedef __attribute__((address_space(1))) void GV;
typedef __attribute__((address_space(3))) void LV;

__device__ __forceinline__ u16 f2bf(float f) {
  union { float f; unsigned u; } v; v.f = f;
  unsigned r = v.u + 0x7FFFu + ((v.u >> 16) & 1u);  // round-to-nearest-even
  return (u16)(r >> 16);
}
__device__ __forceinline__ float bf2f(u16 x) {
  union { unsigned u; float f; } v; v.u = ((unsigned)x) << 16; return v.f;
}

// K-loop LDS map within a rows x 32K u16 region (proven 0-conflict R6-R10):
//   idx = (r>>1)*64 + (r&1)*32 + ((kc ^ ((r>>1)&3))*8) + j
__device__ __forceinline__ int lds_off(int r, int hi) {
  return (r >> 1) * 64 + (r & 1) * 32 + ((hi ^ ((r >> 1) & 3)) * 8);
}
// conv-epilogue LDS map: [c][r] col-major with row-XOR swizzle
__device__ __forceinline__ int fsw(int c, int r) {
  return c * 256 + (r ^ ((c & 31) << 3));
}

// ---------------- kernel 1: row softmax -> bf16 X (row-major) ---------------
__global__ __launch_bounds__(192) void softmax_k(const float* __restrict__ vf,
                                                 u16* __restrict__ X) {
  size_t row = blockIdx.x;
  const float4* p = (const float4*)(vf + row * Dn);
  int t = threadIdx.x;
  float4 v = p[t];
  float mx = fmaxf(fmaxf(v.x, v.y), fmaxf(v.z, v.w));
  #pragma unroll
  for (int off = 32; off; off >>= 1) mx = fmaxf(mx, __shfl_xor(mx, off));
  __shared__ float rr[3];
  __shared__ float rs[3];
  int wv = t >> 6, ln = t & 63;
  if (!ln) rr[wv] = mx;
  __syncthreads();
  mx = fmaxf(fmaxf(rr[0], rr[1]), rr[2]);
  float e0 = __expf(v.x - mx), e1 = __expf(v.y - mx);
  float e2 = __expf(v.z - mx), e3 = __expf(v.w - mx);
  float s = e0 + e1 + e2 + e3;
  #pragma unroll
  for (int off = 32; off; off >>= 1) s += __shfl_xor(s, off);
  if (!ln) rs[wv] = s;
  __syncthreads();
  float inv = 1.0f / (rs[0] + rs[1] + rs[2]);
  ushort4 o;
  o.x = f2bf(e0 * inv); o.y = f2bf(e1 * inv);
  o.z = f2bf(e2 * inv); o.w = f2bf(e3 * inv);
  ((ushort4*)(X + row * Dn))[t] = o;
}

// ------- kernel 2: pack W1/W2 block-of-32 interleaved, bf16 [1536][768] -----
__global__ __launch_bounds__(256) void build_wt_k(const float* __restrict__ W1,
                                                  const float* __restrict__ W2,
                                                  u16* __restrict__ Wt) {
  int idx = blockIdx.x * 256 + threadIdx.x;
  if (idx >= Dn * Dn) return;
  int j = idx / Dn, d = idx - j * Dn;
  int b = j >> 5, c = j & 31;
  Wt[(size_t)(b * 64 + c) * Dn + d]      = f2bf(W1[(size_t)j * Dn + d]);
  Wt[(size_t)(b * 64 + 32 + c) * Dn + d] = f2bf(W2[(size_t)j * Dn + d]);
}

// -------- kernel 3: GEMM, 2 blk/CU + mini-phases + WAR barrier --------------
// 8 waves (4M x 2N), wave tile 64x64, 24 K-slices of 32, 2-slot LDS ring.
// Slice: vmcnt(3) -> barrier -> 4 wave-local mini-phases
//   {b0..b3+a0; lgkm0; SB0; 4 MFMA}{a1; lgkm0; SB0; 4 MFMA}{a2..}{a3..}
// -> BARRIER (write-after-read guard: STAGE overwrites the slot being read
//    this slice — R12 omitted this and raced, absmax 2.7e-3) -> stage s+2.
// Mini-phases keep <=5 ds_reads outstanding per wave and re-enter the LDS
// queue 4x/slice at staggered times (convoy-breaker for the lgkm0 drain).
__global__ __launch_bounds__(512, 4) void gemm_fuse_k(
    const u16* __restrict__ X, const u16* __restrict__ Wt,
    const float* __restrict__ b1, const float* __restrict__ b2,
    const float* __restrict__ text, float* __restrict__ out,
    u16* __restrict__ seam,
    const float* __restrict__ cw1, const float* __restrict__ cb1,
    const float* __restrict__ cw2, const float* __restrict__ cb2) {
  __shared__ __align__(16) u16 smem[32768];   // 64 KiB peak (epilogue)

  const int h = blockIdx.x;                      // GRID = 3840, %8==0
  const int lin = (h & 7) * (GRID / 8) + (h >> 3);
  const int by = lin / NTILES, bx = lin - by * NTILES;
  const int brow = by * BM;

  const int t = threadIdx.x, w = t >> 6, l = t & 63;
  const int lo = l & 15, hi = l >> 4;
  const int wrr = w >> 1, wcc = w & 1;           // 4M x 2N

  int offA[4], offB[4];
  #pragma unroll
  for (int m = 0; m < 4; ++m) offA[m] = lds_off(wrr * 64 + m * 16 + lo, hi);
  #pragma unroll
  for (int n = 0; n < 4; ++n) offB[n] = 8192 + lds_off(wcc * 64 + n * 16 + lo, hi);

  // staging sources: thread q fills u16 [q*8..q*8+8) of a region
  const u16* gA[2];
  const u16* gB;
  #pragma unroll
  for (int ii = 0; ii < 2; ++ii) {
    int q = ii * 512 + t;
    int rp = q >> 3, half = (q >> 2) & 1, kc = (q & 3) ^ (rp & 3);
    gA[ii] = X + (size_t)(brow + rp * 2 + half) * Dn + kc * 8;
  }
  {
    int rp = t >> 3, half = (t >> 2) & 1, kc = (t & 3) ^ (rp & 3);
    gB = Wt + (size_t)(bx * BNt + rp * 2 + half) * Dn + kc * 8;
  }

#define STAGE(SLOT, KOFF) do {                                                 \
    _Pragma("unroll")                                                          \
    for (int ii = 0; ii < 2; ++ii)                                             \
      __builtin_amdgcn_global_load_lds((GV*)(gA[ii] + (KOFF)),                 \
          (LV*)(smem + (SLOT) * SLOTU + (ii * 512 + t) * 8), 16, 0, 0);        \
    __builtin_amdgcn_global_load_lds((GV*)(gB + (KOFF)),                       \
        (LV*)(smem + (SLOT) * SLOTU + 8192 + t * 8), 16, 0, 0);                \
  } while (0)

  // prologue: slices 0,1 (6 loads in flight)
  STAGE(0, 0);
  STAGE(1, HK);

  f32x4 acc[4][4] = {};

#define MINI(G, AF) do {                                                       \
    asm volatile("s_waitcnt lgkmcnt(0)" ::: "memory");                         \
    __builtin_amdgcn_sched_barrier(0);                                         \
    acc[G][0] = __builtin_amdgcn_mfma_f32_16x16x32_bf16(AF, b0_, acc[G][0], 0, 0, 0); \
    acc[G][1] = __builtin_amdgcn_mfma_f32_16x16x32_bf16(AF, b1_, acc[G][1], 0, 0, 0); \
    acc[G][2] = __builtin_amdgcn_mfma_f32_16x16x32_bf16(AF, b2_, acc[G][2], 0, 0, 0); \
    acc[G][3] = __builtin_amdgcn_mfma_f32_16x16x32_bf16(AF, b3_, acc[G][3], 0, 0, 0); \
  } while (0)

  #pragma unroll 2
  for (int hk = 0; hk < NHK; ++hk) {
    if (hk < NHK - 2) asm volatile("s_waitcnt vmcnt(3)" ::: "memory");
    else              asm volatile("s_waitcnt vmcnt(0)" ::: "memory");
    __builtin_amdgcn_s_barrier();
    const u16* sa = smem + (hk & 1) * SLOTU;

    short8 b0_ = *(const short8*)(sa + offB[0]);
    short8 b1_ = *(const short8*)(sa + offB[1]);
    short8 b2_ = *(const short8*)(sa + offB[2]);
    short8 b3_ = *(const short8*)(sa + offB[3]);
    short8 a_  = *(const short8*)(sa + offA[0]);
    __builtin_amdgcn_s_setprio(1);
    MINI(0, a_);
    a_ = *(const short8*)(sa + offA[1]);
    MINI(1, a_);
    a_ = *(const short8*)(sa + offA[2]);
    MINI(2, a_);
    a_ = *(const short8*)(sa + offA[3]);
    MINI(3, a_);
    __builtin_amdgcn_s_setprio(0);

    __builtin_amdgcn_s_barrier();   // WAR guard: all reads of this slot done
    if (hk < NHK - 2) STAGE(hk & 1, (hk + 2) * HK);
  }
#undef MINI
#undef STAGE

  __syncthreads();   // all slot-reads done before LDS reuse by epilogue

  // ======================= fused-conv epilogue ==============================
  const float w10 = cw1[0], w11 = cw1[1], w12 = cw1[2], c1b = cb1[0];
  const float w20 = cw2[0], w21 = cw2[1], w22 = cw2[2], c2b = cb2[0];

  u16* fsm = smem;           // fused [64 c][256 r], swizzled: 32 KiB
  u16* tsm = smem + 16384;   // tmp, same layout: 32 KiB

  // ---- E1: fused -> LDS bf16 (+ seam store for cols 0-3, 60-63) ----
  #pragma unroll
  for (int n = 0; n < 2; ++n) {
    const int cl = wcc * 32 + n * 16 + lo;       // local col 0..63
    const int e  = bx * 64 + cl;
    const float B1 = b1[e], B2 = b2[e];
    #pragma unroll
    for (int m = 0; m < 4; ++m) {
      const int rl = wrr * 64 + m * 16 + hi * 4;
      uint2 pk;
      u16* pku = (u16*)&pk;
      #pragma unroll
      for (int r = 0; r < 4; ++r) {
        const int gr = brow + rl + r;
        const float v1 = acc[m][n][r] + B1;
        const float v2 = acc[m][n + 2][r] + B2;
        const float tf = text[(size_t)(gr / Vn) * Dn + e];
        pku[r] = f2bf(fmaxf(tf * v1 + v2, 0.0f));
      }
      *(uint2*)(fsm + fsw(cl, rl)) = pk;
      const int sidx = (cl < 4) ? cl : ((cl >= 60) ? cl - 56 : -1);
      if (sidx >= 0)
        *(uint2*)(seam + ((size_t)(by * NTILES + bx) * 8 + sidx) * 256 + rl) = pk;
    }
  }
  __syncthreads();

  // ---- E2: tmp = relu(conv1(fused)); own col kept in regs ----
  const int cl = t & 63, rb = t >> 6;            // 8 row-groups of 32
  const int cL = cl ? cl - 1 : 0, cR = (cl < 63) ? cl + 1 : 63;
  short8 tC[4];
  #pragma unroll
  for (int j = 0; j < 4; ++j) {
    const int R = rb * 32 + j * 8;
    short8 sL = *(const short8*)(fsm + fsw(cL, R));
    short8 sC = *(const short8*)(fsm + fsw(cl, R));
    short8 sR = *(const short8*)(fsm + fsw(cR, R));
    short8 o;
    #pragma unroll
    for (int k = 0; k < 8; ++k) {
      float a = bf2f((u16)sL[k]), b = bf2f((u16)sC[k]), c = bf2f((u16)sR[k]);
      o[k] = (short)f2bf(fmaxf(fmaf(w10, a, fmaf(w11, b, fmaf(w12, c, c1b))), 0.0f));
    }
    *(short8*)(tsm + fsw(cl, R)) = o;
    tC[j] = o;
  }
  __syncthreads();

  // ---- E3: out = conv2(tmp), store interior cols 2..61 ----
  const bool wr_ok = (cl >= 2 && cl <= 61);
  #pragma unroll
  for (int j = 0; j < 4; ++j) {
    const int R = rb * 32 + j * 8;
    short8 tL = *(const short8*)(tsm + fsw(cL, R));
    short8 tR = *(const short8*)(tsm + fsw(cR, R));
    #pragma unroll
    for (int k = 0; k < 8; ++k) {
      float v = fmaf(w20, bf2f((u16)tL[k]),
                fmaf(w21, bf2f((u16)tC[j][k]),
                fmaf(w22, bf2f((u16)tR[k]), c2b)));
      if (wr_ok)
        out[(size_t)(brow + R + k) * Dn + bx * 64 + cl] = v;
    }
  }
}

// ------- kernel 4: seam cleanup — out cols {E0,E0+1,E0+62,E0+63} -----------
__global__ __launch_bounds__(256) void seam_k(const u16* __restrict__ seam,
                                              float* __restrict__ out,
                                              const float* __restrict__ cw1,
                                              const float* __restrict__ cb1,
                                              const float* __restrict__ cw2,
                                              const float* __restrict__ cb2) {
  const int bid = blockIdx.x;          // by*12+bx
  const int by = bid / NTILES, bx = bid - by * NTILES;
  const int r = threadIdx.x;
  const float w10 = cw1[0], w11 = cw1[1], w12 = cw1[2], c1b = cb1[0];
  const float w20 = cw2[0], w21 = cw2[1], w22 = cw2[2], c2b = cb2[0];
  #define SM(B, I) bf2f(seam[((size_t)(B) * 8 + (I)) * 256 + r])
  float fm2 = 0.f, fm1 = 0.f, fR0 = 0.f, fR1 = 0.f;
  if (bx > 0)          { fm2 = SM(bid - 1, 6); fm1 = SM(bid - 1, 7); }
  if (bx < NTILES - 1) { fR0 = SM(bid + 1, 0); fR1 = SM(bid + 1, 1); }
  const float f0 = SM(bid, 0), f1 = SM(bid, 1), f2 = SM(bid, 2), f3 = SM(bid, 3);
  const float f60 = SM(bid, 4), f61 = SM(bid, 5), f62 = SM(bid, 6), f63 = SM(bid, 7);
  #undef SM
  #define C1(a, b, c) fmaxf(fmaf(w10, (a), fmaf(w11, (b), fmaf(w12, (c), c1b))), 0.0f)
  const float tm1 = (bx > 0) ? C1(fm2, fm1, f0) : 0.0f;
  const float t0  = C1(fm1, f0, f1);
  const float t1  = C1(f0, f1, f2);
  const float t2  = C1(f1, f2, f3);
  const float t61 = C1(f60, f61, f62);
  const float t62 = C1(f61, f62, f63);
  const float t63 = C1(f62, f63, fR0);
  const float t64 = (bx < NTILES - 1) ? C1(f63, fR0, fR1) : 0.0f;
  #undef C1
  const size_t go = (size_t)(by * 256 + r) * Dn + bx * 64;
  out[go + 0]  = fmaf(w20, tm1, fmaf(w21, t0,  fmaf(w22, t1,  c2b)));
  out[go + 1]  = fmaf(w20, t0,  fmaf(w21, t1,  fmaf(w22, t2,  c2b)));
  out[go + 62] = fmaf(w20, t61, fmaf(w21, t62, fmaf(w22, t63, c2b)));
  out[go + 63] = fmaf(w20, t62, fmaf(w21, t63, fmaf(w22, t64, c2b)));
}

extern "C" void kernel_launch(void* const* d_in, const int* in_sizes, int n_in,
                              void* d_out, int out_size, void* d_ws, size_t ws_size,
                              hipStream_t stream) {
  const float* text = (const float*)d_in[0];
  const float* vf   = (const float*)d_in[1];
  const float* W1   = (const float*)d_in[2];
  const float* b1   = (const float*)d_in[3];
  const float* W2   = (const float*)d_in[4];
  const float* b2   = (const float*)d_in[5];
  const float* cw1  = (const float*)d_in[6];
  const float* cb1  = (const float*)d_in[7];
  const float* cw2  = (const float*)d_in[8];
  const float* cb2  = (const float*)d_in[9];
  float* out = (float*)d_out;

  u16* X    = (u16*)d_ws;                        // [81920][768] bf16
  u16* Wt   = X + (size_t)Mn * Dn;               // [1536][768] bf16
  u16* seam = Wt + (size_t)Nn * Dn;              // [3840][8][256] bf16

  softmax_k<<<Mn, 192, 0, stream>>>(vf, X);
  build_wt_k<<<(Dn * Dn + 255) / 256, 256, 0, stream>>>(W1, W2, Wt);
  gemm_fuse_k<<<GRID, 512, 0, stream>>>(X, Wt, b1, b2, text, out, seam,
                                        cw1, cb1, cw2, cb2);
  seam_k<<<GRID, 256, 0, stream>>>(seam, out, cw1, cb1, cw2, cb2);
}